// Round 8
// baseline (80.284 us; speedup 1.0000x reference)
//
#include <hip/hip_runtime.h>

#define NN 4096
#define LOG2E 1.44269504088896340736f
#define EXP2(x) __builtin_amdgcn_exp2f(x)

typedef float f32x4 __attribute__((ext_vector_type(4)));

// ---------------------------------------------------------------------------
// Kernel A: per-row stats. Grid (NN/64, nb), block 256. Block stages the full
// 4096-score row (16 KB), 4 threads per row each sum a k-quarter of
// |s_i - s_k|, LDS-merge, emit u = -s*log2e, vl = B*log2e.
__global__ __launch_bounds__(256) void k_rows(const float* __restrict__ scores,
                                              float* __restrict__ u,
                                              float* __restrict__ vl, int nb) {
    __shared__ float sch[NN];
    __shared__ float part[4][64];
    const int b = blockIdx.y, t = threadIdx.x;
    const float* srow = scores + (size_t)b * NN;
    for (int q = t * 4; q < NN; q += 1024)
        *reinterpret_cast<float4*>(&sch[q]) =
            *reinterpret_cast<const float4*>(&srow[q]);
    __syncthreads();
    const int r = t & 63;                  // row within block
    const int q = t >> 6;                  // k-quarter (uniform per wave)
    const float si = sch[blockIdx.x * 64 + r];
    float a0=0.f,a1=0.f,a2=0.f,a3=0.f,a4=0.f,a5=0.f,a6=0.f,a7=0.f;
    const int k0 = q * (NN / 4);
    for (int k = k0; k < k0 + NN / 4; k += 8) {
        float4 x = *reinterpret_cast<const float4*>(&sch[k]);
        float4 y = *reinterpret_cast<const float4*>(&sch[k + 4]);
        a0 += fabsf(si - x.x); a1 += fabsf(si - x.y);
        a2 += fabsf(si - x.z); a3 += fabsf(si - x.w);
        a4 += fabsf(si - y.x); a5 += fabsf(si - y.y);
        a6 += fabsf(si - y.z); a7 += fabsf(si - y.w);
    }
    part[q][r] = ((a0 + a1) + (a2 + a3)) + ((a4 + a5) + (a6 + a7));
    __syncthreads();
    if (t < 64) {
        const int ii = blockIdx.x * 64 + t;
        const float B = (part[0][t] + part[1][t]) + (part[2][t] + part[3][t]);
        u[(size_t)b * NN + ii]  = -sch[ii] * LOG2E;
        vl[(size_t)b * NN + ii] = B * LOG2E;
    }
}

// ---------------------------------------------------------------------------
// Kernel B: per-column softmax constant. Grid (NN/32, nb), block 256.
// Stage u and -v in LDS (32 KB); 8 threads per column, two passes (max,
// sum-of-exp2) with LDS merges. Emits w[b,j] = -m_j - log2(Z_j).
__global__ __launch_bounds__(256) void k_cols(const float* __restrict__ u,
                                              const float* __restrict__ vl,
                                              float* __restrict__ w, int nb) {
    __shared__ float su[NN];
    __shared__ float sv[NN];
    __shared__ float pm[8][32];
    __shared__ float pz[8][32];
    __shared__ float fm[32];
    const int b = blockIdx.y, t = threadIdx.x;
    const size_t base = (size_t)b * NN;
    for (int q4 = t * 4; q4 < NN; q4 += 1024) {
        float4 uu = *reinterpret_cast<const float4*>(&u[base + q4]);
        float4 vv = *reinterpret_cast<const float4*>(&vl[base + q4]);
        *reinterpret_cast<float4*>(&su[q4]) = uu;
        sv[q4] = -vv.x; sv[q4+1] = -vv.y; sv[q4+2] = -vv.z; sv[q4+3] = -vv.w;
    }
    __syncthreads();
    const int c = t & 31, q = t >> 5;
    const int j = blockIdx.x * 32 + c;
    const float cj = (float)(NN - 1 - 2 * j);
    const float4* su4 = reinterpret_cast<const float4*>(su);
    const float4* sv4 = reinterpret_cast<const float4*>(sv);
    const int i40 = q * (NN / 8) / 4, i41 = i40 + (NN / 8) / 4;
    float m0 = -3.4e38f, m1 = -3.4e38f;
    for (int i4 = i40; i4 < i41; ++i4) {
        float4 uu = su4[i4], vv = sv4[i4];
        m0 = fmaxf(m0, fmaf(uu.x, cj, vv.x));
        m1 = fmaxf(m1, fmaf(uu.y, cj, vv.y));
        m0 = fmaxf(m0, fmaf(uu.z, cj, vv.z));
        m1 = fmaxf(m1, fmaf(uu.w, cj, vv.w));
    }
    pm[q][c] = fmaxf(m0, m1);
    __syncthreads();
    if (t < 32) {
        float m = pm[0][t];
#pragma unroll
        for (int k = 1; k < 8; k++) m = fmaxf(m, pm[k][t]);
        fm[t] = m;
    }
    __syncthreads();
    const float m = fm[c];
    float z0 = 0.f, z1 = 0.f;
    for (int i4 = i40; i4 < i41; ++i4) {
        float4 uu = su4[i4], vv = sv4[i4];
        z0 += EXP2(fmaf(uu.x, cj, vv.x) - m);
        z1 += EXP2(fmaf(uu.y, cj, vv.y) - m);
        z0 += EXP2(fmaf(uu.z, cj, vv.z) - m);
        z1 += EXP2(fmaf(uu.w, cj, vv.w) - m);
    }
    pz[q][c] = z0 + z1;
    __syncthreads();
    if (t < 32) {
        float z = 0.f;
#pragma unroll
        for (int k = 0; k < 8; k++) z += pz[k][t];
        w[base + blockIdx.x * 32 + t] = -fm[t] - log2f(z);
    }
}

// ---------------------------------------------------------------------------
// Kernel C: out[b,i,j] = exp2(fma(u_i, c_j, w_j - v_i)).
// Grid (NN/1024, NN/32, nb), block 256; thread owns 4 consecutive columns —
// one contiguous float4 per row, full 1 KiB-dense wave stores (same layout
// as R4/R7). Geometric chain along j (1 exp + 6 mul per row). NEW vs R7:
// nontemporal stores — out (268 MB) == L3 capacity, so regular stores
// allocate+dirty-evict every line; nt bypasses that churn.
__global__ __launch_bounds__(256) void k_out(const float* __restrict__ u,
                                             const float* __restrict__ vl,
                                             const float* __restrict__ w,
                                             float* __restrict__ out, int nb) {
    __shared__ float su[32], sv[32], sg[32];
    const int b = blockIdx.z, jc = blockIdx.x, t = threadIdx.x;
    const int i0 = blockIdx.y * 32;
    if (t < 32) {
        const float uu = u[(size_t)b * NN + i0 + t];
        su[t] = uu;
        sv[t] = vl[(size_t)b * NN + i0 + t];
        sg[t] = EXP2(-2.0f * uu);
    }
    const int j = jc * 1024 + t * 4;
    const float4 w4 = *reinterpret_cast<const float4*>(w + (size_t)b * NN + j);
    const float d1 = EXP2(w4.y - w4.x);
    const float d2 = EXP2(w4.z - w4.y);
    const float d3 = EXP2(w4.w - w4.z);
    const float c0 = (float)(NN - 1 - 2 * j);
    __syncthreads();
    float* orow = out + ((size_t)b * NN + i0) * NN + j;
#pragma unroll 4
    for (int r = 0; r < 32; r++) {
        const float ui = su[r], vi = sv[r], gi = sg[r];
        f32x4 o;
        o.x = EXP2(fmaf(ui, c0, w4.x - vi));
        o.y = o.x * (gi * d1);
        o.z = o.y * (gi * d2);
        o.w = o.z * (gi * d3);
        __builtin_nontemporal_store(o, reinterpret_cast<f32x4*>(orow + (size_t)r * NN));
    }
}

// ---------------------------------------------------------------------------
extern "C" void kernel_launch(void* const* d_in, const int* in_sizes, int n_in,
                              void* d_out, int out_size, void* d_ws, size_t ws_size,
                              hipStream_t stream) {
    const float* scores = (const float*)d_in[0];
    float* out = (float*)d_out;
    const int nb = in_sizes[0] / NN;          // 4 batches
    const size_t S = (size_t)nb * NN;

    float* ws = (float*)d_ws;                 // 3*S floats = 192 KiB
    float* u  = ws;
    float* vl = u + S;
    float* w  = vl + S;

    hipLaunchKernelGGL(k_rows, dim3(NN / 64, nb), dim3(256), 0, stream,
                       scores, u, vl, nb);
    hipLaunchKernelGGL(k_cols, dim3(NN / 32, nb), dim3(256), 0, stream,
                       u, vl, w, nb);
    hipLaunchKernelGGL(k_out, dim3(NN / 1024, NN / 32, nb), dim3(256), 0, stream,
                       u, vl, w, out, nb);
}

// Round 9
// 65.756 us; speedup vs baseline: 1.2209x; 1.2209x over previous
//
#include <hip/hip_runtime.h>

#define NN 4096
#define LOG2E 1.44269504088896340736f
#define EXP2(x) __builtin_amdgcn_exp2f(x)

// ---------------------------------------------------------------------------
// Kernel A: per-row stats. Grid (NN/64, nb), block 256. Block stages the full
// 4096-score row (16 KB), 4 threads per row each sum a k-quarter of
// |s_i - s_k|, LDS-merge, emit u = -s*log2e, vl = B*log2e.
__global__ __launch_bounds__(256) void k_rows(const float* __restrict__ scores,
                                              float* __restrict__ u,
                                              float* __restrict__ vl, int nb) {
    __shared__ float sch[NN];
    __shared__ float part[4][64];
    const int b = blockIdx.y, t = threadIdx.x;
    const float* srow = scores + (size_t)b * NN;
    for (int q = t * 4; q < NN; q += 1024)
        *reinterpret_cast<float4*>(&sch[q]) =
            *reinterpret_cast<const float4*>(&srow[q]);
    __syncthreads();
    const int r = t & 63;                  // row within block
    const int q = t >> 6;                  // k-quarter (uniform per wave)
    const float si = sch[blockIdx.x * 64 + r];
    float a0=0.f,a1=0.f,a2=0.f,a3=0.f,a4=0.f,a5=0.f,a6=0.f,a7=0.f;
    const int k0 = q * (NN / 4);
    for (int k = k0; k < k0 + NN / 4; k += 8) {
        float4 x = *reinterpret_cast<const float4*>(&sch[k]);
        float4 y = *reinterpret_cast<const float4*>(&sch[k + 4]);
        a0 += fabsf(si - x.x); a1 += fabsf(si - x.y);
        a2 += fabsf(si - x.z); a3 += fabsf(si - x.w);
        a4 += fabsf(si - y.x); a5 += fabsf(si - y.y);
        a6 += fabsf(si - y.z); a7 += fabsf(si - y.w);
    }
    part[q][r] = ((a0 + a1) + (a2 + a3)) + ((a4 + a5) + (a6 + a7));
    __syncthreads();
    if (t < 64) {
        const int ii = blockIdx.x * 64 + t;
        const float B = (part[0][t] + part[1][t]) + (part[2][t] + part[3][t]);
        u[(size_t)b * NN + ii]  = -sch[ii] * LOG2E;
        vl[(size_t)b * NN + ii] = B * LOG2E;
    }
}

// ---------------------------------------------------------------------------
// Kernel B: per-column softmax constant. Grid (NN/32, nb), block 256.
// NEW: 4 columns per thread (register blocking) -> LDS traffic /4.
// Thread (g = t&7, q = t>>3): g picks 4 cols of the block's 32, q picks an
// interleaved set of 32 float4s (i4 = q + 32k) -> per-wave the 8 distinct
// addresses hit 8 distinct 4-bank groups (bank-conflict-free, 8-lane
// broadcast). Two passes (max, sum-of-exp2) + [32][32] LDS merges.
// Emits w[b,j] = -m_j - log2(Z_j).
__global__ __launch_bounds__(256) void k_cols(const float* __restrict__ u,
                                              const float* __restrict__ vl,
                                              float* __restrict__ w, int nb) {
    __shared__ float su[NN];
    __shared__ float sv[NN];
    __shared__ float pm[32][32];
    __shared__ float pz[32][32];
    __shared__ float fm[32];
    const int b = blockIdx.y, t = threadIdx.x;
    const size_t base = (size_t)b * NN;
    for (int q4 = t * 4; q4 < NN; q4 += 1024) {
        float4 uu = *reinterpret_cast<const float4*>(&u[base + q4]);
        float4 vv = *reinterpret_cast<const float4*>(&vl[base + q4]);
        *reinterpret_cast<float4*>(&su[q4]) = uu;
        sv[q4] = -vv.x; sv[q4+1] = -vv.y; sv[q4+2] = -vv.z; sv[q4+3] = -vv.w;
    }
    __syncthreads();
    const int g = t & 7;                   // column group: 4 cols
    const int q = t >> 3;                  // i-chunk selector (32 chunks)
    const int j0 = blockIdx.x * 32 + g * 4;
    const float c0 = (float)(NN - 1 - 2 * j0);
    const float c1 = c0 - 2.f, c2 = c0 - 4.f, c3 = c0 - 6.f;
    const float4* su4 = reinterpret_cast<const float4*>(su);
    const float4* sv4 = reinterpret_cast<const float4*>(sv);
    float M0 = -3.4e38f, M1 = -3.4e38f, M2 = -3.4e38f, M3 = -3.4e38f;
    for (int k = 0; k < 32; ++k) {
        const int i4 = q + 32 * k;         // interleaved -> conflict-free
        float4 uu = su4[i4], vv = sv4[i4];
        M0 = fmaxf(M0, fmaf(uu.x, c0, vv.x)); M0 = fmaxf(M0, fmaf(uu.y, c0, vv.y));
        M0 = fmaxf(M0, fmaf(uu.z, c0, vv.z)); M0 = fmaxf(M0, fmaf(uu.w, c0, vv.w));
        M1 = fmaxf(M1, fmaf(uu.x, c1, vv.x)); M1 = fmaxf(M1, fmaf(uu.y, c1, vv.y));
        M1 = fmaxf(M1, fmaf(uu.z, c1, vv.z)); M1 = fmaxf(M1, fmaf(uu.w, c1, vv.w));
        M2 = fmaxf(M2, fmaf(uu.x, c2, vv.x)); M2 = fmaxf(M2, fmaf(uu.y, c2, vv.y));
        M2 = fmaxf(M2, fmaf(uu.z, c2, vv.z)); M2 = fmaxf(M2, fmaf(uu.w, c2, vv.w));
        M3 = fmaxf(M3, fmaf(uu.x, c3, vv.x)); M3 = fmaxf(M3, fmaf(uu.y, c3, vv.y));
        M3 = fmaxf(M3, fmaf(uu.z, c3, vv.z)); M3 = fmaxf(M3, fmaf(uu.w, c3, vv.w));
    }
    *reinterpret_cast<float4*>(&pm[q][g * 4]) = make_float4(M0, M1, M2, M3);
    __syncthreads();
    if (t < 32) {
        float m = pm[0][t];
#pragma unroll
        for (int k = 1; k < 32; k++) m = fmaxf(m, pm[k][t]);
        fm[t] = m;
    }
    __syncthreads();
    const float m0 = fm[g * 4], m1 = fm[g * 4 + 1];
    const float m2 = fm[g * 4 + 2], m3 = fm[g * 4 + 3];
    float Z0 = 0.f, Z1 = 0.f, Z2 = 0.f, Z3 = 0.f;
    for (int k = 0; k < 32; ++k) {
        const int i4 = q + 32 * k;
        float4 uu = su4[i4], vv = sv4[i4];
        Z0 += EXP2(fmaf(uu.x, c0, vv.x) - m0); Z0 += EXP2(fmaf(uu.y, c0, vv.y) - m0);
        Z0 += EXP2(fmaf(uu.z, c0, vv.z) - m0); Z0 += EXP2(fmaf(uu.w, c0, vv.w) - m0);
        Z1 += EXP2(fmaf(uu.x, c1, vv.x) - m1); Z1 += EXP2(fmaf(uu.y, c1, vv.y) - m1);
        Z1 += EXP2(fmaf(uu.z, c1, vv.z) - m1); Z1 += EXP2(fmaf(uu.w, c1, vv.w) - m1);
        Z2 += EXP2(fmaf(uu.x, c2, vv.x) - m2); Z2 += EXP2(fmaf(uu.y, c2, vv.y) - m2);
        Z2 += EXP2(fmaf(uu.z, c2, vv.z) - m2); Z2 += EXP2(fmaf(uu.w, c2, vv.w) - m2);
        Z3 += EXP2(fmaf(uu.x, c3, vv.x) - m3); Z3 += EXP2(fmaf(uu.y, c3, vv.y) - m3);
        Z3 += EXP2(fmaf(uu.z, c3, vv.z) - m3); Z3 += EXP2(fmaf(uu.w, c3, vv.w) - m3);
    }
    *reinterpret_cast<float4*>(&pz[q][g * 4]) = make_float4(Z0, Z1, Z2, Z3);
    __syncthreads();
    if (t < 32) {
        float z = 0.f;
#pragma unroll
        for (int k = 0; k < 32; k++) z += pz[k][t];
        w[base + blockIdx.x * 32 + t] = -fm[t] - log2f(z);
    }
}

// ---------------------------------------------------------------------------
// Kernel C (= R7, proven best): out[b,i,j] = exp2(fma(u_i, c_j, w_j - v_i)).
// Grid (NN/1024, NN/32, nb), block 256; thread owns 4 consecutive columns
// (one contiguous float4 store per row, regular stores). Geometric chain
// along j: 1 exp + 6 mul per row.
__global__ __launch_bounds__(256) void k_out(const float* __restrict__ u,
                                             const float* __restrict__ vl,
                                             const float* __restrict__ w,
                                             float* __restrict__ out, int nb) {
    __shared__ float su[32], sv[32], sg[32];
    const int b = blockIdx.z, jc = blockIdx.x, t = threadIdx.x;
    const int i0 = blockIdx.y * 32;
    if (t < 32) {
        const float uu = u[(size_t)b * NN + i0 + t];
        su[t] = uu;
        sv[t] = vl[(size_t)b * NN + i0 + t];
        sg[t] = EXP2(-2.0f * uu);
    }
    const int j = jc * 1024 + t * 4;
    const float4 w4 = *reinterpret_cast<const float4*>(w + (size_t)b * NN + j);
    const float d1 = EXP2(w4.y - w4.x);
    const float d2 = EXP2(w4.z - w4.y);
    const float d3 = EXP2(w4.w - w4.z);
    const float c0 = (float)(NN - 1 - 2 * j);
    __syncthreads();
    float* orow = out + ((size_t)b * NN + i0) * NN + j;
#pragma unroll 4
    for (int r = 0; r < 32; r++) {
        const float ui = su[r], vi = sv[r], gi = sg[r];
        float4 o;
        o.x = EXP2(fmaf(ui, c0, w4.x - vi));
        o.y = o.x * (gi * d1);
        o.z = o.y * (gi * d2);
        o.w = o.z * (gi * d3);
        *reinterpret_cast<float4*>(orow + (size_t)r * NN) = o;
    }
}

// ---------------------------------------------------------------------------
extern "C" void kernel_launch(void* const* d_in, const int* in_sizes, int n_in,
                              void* d_out, int out_size, void* d_ws, size_t ws_size,
                              hipStream_t stream) {
    const float* scores = (const float*)d_in[0];
    float* out = (float*)d_out;
    const int nb = in_sizes[0] / NN;          // 4 batches
    const size_t S = (size_t)nb * NN;

    float* ws = (float*)d_ws;                 // 3*S floats = 192 KiB
    float* u  = ws;
    float* vl = u + S;
    float* w  = vl + S;

    hipLaunchKernelGGL(k_rows, dim3(NN / 64, nb), dim3(256), 0, stream,
                       scores, u, vl, nb);
    hipLaunchKernelGGL(k_cols, dim3(NN / 32, nb), dim3(256), 0, stream,
                       u, vl, w, nb);
    hipLaunchKernelGGL(k_out, dim3(NN / 1024, NN / 32, nb), dim3(256), 0, stream,
                       u, vl, w, out, nb);
}

// Round 10
// 65.574 us; speedup vs baseline: 1.2243x; 1.0028x over previous
//
#include <hip/hip_runtime.h>

#define NN 4096
#define LOG2E 1.44269504088896340736f
#define EXP2(x) __builtin_amdgcn_exp2f(x)

// ---------------------------------------------------------------------------
// Kernel A: per-row stats. Grid (NN/64, nb), block 256. Block stages the full
// 4096-score row (16 KB), 4 threads per row each sum a k-quarter of
// |s_i - s_k|, LDS-merge, emit u = -s*log2e, vl = B*log2e.
__global__ __launch_bounds__(256) void k_rows(const float* __restrict__ scores,
                                              float* __restrict__ u,
                                              float* __restrict__ vl, int nb) {
    __shared__ float sch[NN];
    __shared__ float part[4][64];
    const int b = blockIdx.y, t = threadIdx.x;
    const float* srow = scores + (size_t)b * NN;
    for (int q = t * 4; q < NN; q += 1024)
        *reinterpret_cast<float4*>(&sch[q]) =
            *reinterpret_cast<const float4*>(&srow[q]);
    __syncthreads();
    const int r = t & 63;                  // row within block
    const int q = t >> 6;                  // k-quarter (uniform per wave)
    const float si = sch[blockIdx.x * 64 + r];
    float a0=0.f,a1=0.f,a2=0.f,a3=0.f,a4=0.f,a5=0.f,a6=0.f,a7=0.f;
    const int k0 = q * (NN / 4);
    for (int k = k0; k < k0 + NN / 4; k += 8) {
        float4 x = *reinterpret_cast<const float4*>(&sch[k]);
        float4 y = *reinterpret_cast<const float4*>(&sch[k + 4]);
        a0 += fabsf(si - x.x); a1 += fabsf(si - x.y);
        a2 += fabsf(si - x.z); a3 += fabsf(si - x.w);
        a4 += fabsf(si - y.x); a5 += fabsf(si - y.y);
        a6 += fabsf(si - y.z); a7 += fabsf(si - y.w);
    }
    part[q][r] = ((a0 + a1) + (a2 + a3)) + ((a4 + a5) + (a6 + a7));
    __syncthreads();
    if (t < 64) {
        const int ii = blockIdx.x * 64 + t;
        const float B = (part[0][t] + part[1][t]) + (part[2][t] + part[3][t]);
        u[(size_t)b * NN + ii]  = -sch[ii] * LOG2E;
        vl[(size_t)b * NN + ii] = B * LOG2E;
    }
}

// ---------------------------------------------------------------------------
// Kernel B (= R9): per-column softmax constant, 4 cols/thread register
// blocking, interleaved conflict-free LDS reads. Emits w = -m - log2(Z).
__global__ __launch_bounds__(256) void k_cols(const float* __restrict__ u,
                                              const float* __restrict__ vl,
                                              float* __restrict__ w, int nb) {
    __shared__ float su[NN];
    __shared__ float sv[NN];
    __shared__ float pm[32][32];
    __shared__ float pz[32][32];
    __shared__ float fm[32];
    const int b = blockIdx.y, t = threadIdx.x;
    const size_t base = (size_t)b * NN;
    for (int q4 = t * 4; q4 < NN; q4 += 1024) {
        float4 uu = *reinterpret_cast<const float4*>(&u[base + q4]);
        float4 vv = *reinterpret_cast<const float4*>(&vl[base + q4]);
        *reinterpret_cast<float4*>(&su[q4]) = uu;
        sv[q4] = -vv.x; sv[q4+1] = -vv.y; sv[q4+2] = -vv.z; sv[q4+3] = -vv.w;
    }
    __syncthreads();
    const int g = t & 7;                   // column group: 4 cols
    const int q = t >> 3;                  // i-chunk selector (32 chunks)
    const int j0 = blockIdx.x * 32 + g * 4;
    const float c0 = (float)(NN - 1 - 2 * j0);
    const float c1 = c0 - 2.f, c2 = c0 - 4.f, c3 = c0 - 6.f;
    const float4* su4 = reinterpret_cast<const float4*>(su);
    const float4* sv4 = reinterpret_cast<const float4*>(sv);
    float M0 = -3.4e38f, M1 = -3.4e38f, M2 = -3.4e38f, M3 = -3.4e38f;
    for (int k = 0; k < 32; ++k) {
        const int i4 = q + 32 * k;         // interleaved -> conflict-free
        float4 uu = su4[i4], vv = sv4[i4];
        M0 = fmaxf(M0, fmaf(uu.x, c0, vv.x)); M0 = fmaxf(M0, fmaf(uu.y, c0, vv.y));
        M0 = fmaxf(M0, fmaf(uu.z, c0, vv.z)); M0 = fmaxf(M0, fmaf(uu.w, c0, vv.w));
        M1 = fmaxf(M1, fmaf(uu.x, c1, vv.x)); M1 = fmaxf(M1, fmaf(uu.y, c1, vv.y));
        M1 = fmaxf(M1, fmaf(uu.z, c1, vv.z)); M1 = fmaxf(M1, fmaf(uu.w, c1, vv.w));
        M2 = fmaxf(M2, fmaf(uu.x, c2, vv.x)); M2 = fmaxf(M2, fmaf(uu.y, c2, vv.y));
        M2 = fmaxf(M2, fmaf(uu.z, c2, vv.z)); M2 = fmaxf(M2, fmaf(uu.w, c2, vv.w));
        M3 = fmaxf(M3, fmaf(uu.x, c3, vv.x)); M3 = fmaxf(M3, fmaf(uu.y, c3, vv.y));
        M3 = fmaxf(M3, fmaf(uu.z, c3, vv.z)); M3 = fmaxf(M3, fmaf(uu.w, c3, vv.w));
    }
    *reinterpret_cast<float4*>(&pm[q][g * 4]) = make_float4(M0, M1, M2, M3);
    __syncthreads();
    if (t < 32) {
        float m = pm[0][t];
#pragma unroll
        for (int k = 1; k < 32; k++) m = fmaxf(m, pm[k][t]);
        fm[t] = m;
    }
    __syncthreads();
    const float m0 = fm[g * 4], m1 = fm[g * 4 + 1];
    const float m2 = fm[g * 4 + 2], m3 = fm[g * 4 + 3];
    float Z0 = 0.f, Z1 = 0.f, Z2 = 0.f, Z3 = 0.f;
    for (int k = 0; k < 32; ++k) {
        const int i4 = q + 32 * k;
        float4 uu = su4[i4], vv = sv4[i4];
        Z0 += EXP2(fmaf(uu.x, c0, vv.x) - m0); Z0 += EXP2(fmaf(uu.y, c0, vv.y) - m0);
        Z0 += EXP2(fmaf(uu.z, c0, vv.z) - m0); Z0 += EXP2(fmaf(uu.w, c0, vv.w) - m0);
        Z1 += EXP2(fmaf(uu.x, c1, vv.x) - m1); Z1 += EXP2(fmaf(uu.y, c1, vv.y) - m1);
        Z1 += EXP2(fmaf(uu.z, c1, vv.z) - m1); Z1 += EXP2(fmaf(uu.w, c1, vv.w) - m1);
        Z2 += EXP2(fmaf(uu.x, c2, vv.x) - m2); Z2 += EXP2(fmaf(uu.y, c2, vv.y) - m2);
        Z2 += EXP2(fmaf(uu.z, c2, vv.z) - m2); Z2 += EXP2(fmaf(uu.w, c2, vv.w) - m2);
        Z3 += EXP2(fmaf(uu.x, c3, vv.x) - m3); Z3 += EXP2(fmaf(uu.y, c3, vv.y) - m3);
        Z3 += EXP2(fmaf(uu.z, c3, vv.z) - m3); Z3 += EXP2(fmaf(uu.w, c3, vv.w) - m3);
    }
    *reinterpret_cast<float4*>(&pz[q][g * 4]) = make_float4(Z0, Z1, Z2, Z3);
    __syncthreads();
    if (t < 32) {
        float z = 0.f;
#pragma unroll
        for (int k = 0; k < 32; k++) z += pz[k][t];
        w[base + blockIdx.x * 32 + t] = -fm[t] - log2f(z);
    }
}

// ---------------------------------------------------------------------------
// Kernel C: out[b,i,j] = exp2(fma(u_i, c_j, w_j - v_i)) via geometric chain.
// NEW mapping: grid (NN/8, nb), block 256 — each block owns 8 FULL rows =
// 128 KB of contiguous output. Row iteration writes the whole 16 KB row
// (4 chunks x 4 KB, chunk inner) before stepping rows, so the block's store
// stream is sequential (matches the fill kernel's locality). Per-thread
// math identical to R7: per chunk, 1 exp anchor + geometric chain.
__global__ __launch_bounds__(256) void k_out(const float* __restrict__ u,
                                             const float* __restrict__ vl,
                                             const float* __restrict__ w,
                                             float* __restrict__ out, int nb) {
    __shared__ float su[8], sv[8], sg[8];
    const int b = blockIdx.y, t = threadIdx.x;
    const int i0 = blockIdx.x * 8;
    if (t < 8) {
        const float uu = u[(size_t)b * NN + i0 + t];
        su[t] = uu;
        sv[t] = vl[(size_t)b * NN + i0 + t];
        sg[t] = EXP2(-2.0f * uu);
    }
    // Per-chunk constants (statically indexed; stays in registers).
    float4 w4[4];
    float d1[4], d2[4], d3[4], cc[4];
    const float* wrow = w + (size_t)b * NN;
#pragma unroll
    for (int c = 0; c < 4; ++c) {
        const int j = c * 1024 + t * 4;
        w4[c] = *reinterpret_cast<const float4*>(wrow + j);
        d1[c] = EXP2(w4[c].y - w4[c].x);
        d2[c] = EXP2(w4[c].z - w4[c].y);
        d3[c] = EXP2(w4[c].w - w4[c].z);
        cc[c] = (float)(NN - 1 - 2 * j);
    }
    __syncthreads();
    float* obase = out + ((size_t)b * NN + i0) * NN;
    for (int r = 0; r < 8; ++r) {
        const float ui = su[r], vi = sv[r], gi = sg[r];
        float* orow = obase + (size_t)r * NN;
#pragma unroll
        for (int c = 0; c < 4; ++c) {
            float4 o;
            o.x = EXP2(fmaf(ui, cc[c], w4[c].x - vi));
            o.y = o.x * (gi * d1[c]);
            o.z = o.y * (gi * d2[c]);
            o.w = o.z * (gi * d3[c]);
            *reinterpret_cast<float4*>(orow + c * 1024 + t * 4) = o;
        }
    }
}

// ---------------------------------------------------------------------------
extern "C" void kernel_launch(void* const* d_in, const int* in_sizes, int n_in,
                              void* d_out, int out_size, void* d_ws, size_t ws_size,
                              hipStream_t stream) {
    const float* scores = (const float*)d_in[0];
    float* out = (float*)d_out;
    const int nb = in_sizes[0] / NN;          // 4 batches
    const size_t S = (size_t)nb * NN;

    float* ws = (float*)d_ws;                 // 3*S floats = 192 KiB
    float* u  = ws;
    float* vl = u + S;
    float* w  = vl + S;

    hipLaunchKernelGGL(k_rows, dim3(NN / 64, nb), dim3(256), 0, stream,
                       scores, u, vl, nb);
    hipLaunchKernelGGL(k_cols, dim3(NN / 32, nb), dim3(256), 0, stream,
                       u, vl, w, nb);
    hipLaunchKernelGGL(k_out, dim3(NN / 8, nb), dim3(256), 0, stream,
                       u, vl, w, out, nb);
}

// Round 12
// 65.469 us; speedup vs baseline: 1.2263x; 1.0016x over previous
//
#include <hip/hip_runtime.h>

#define NN 4096
#define LOG2E 1.44269504088896340736f
#define EXP2(x) __builtin_amdgcn_exp2f(x)

// ---------------------------------------------------------------------------
// Kernel A: per-row stats. Grid (NN/64, nb), block 256. Block stages the full
// 4096-score row (16 KB), 4 threads per row each sum a k-quarter of
// |s_i - s_k|, LDS-merge, emit u = -s*log2e, vl = B*log2e.
__global__ __launch_bounds__(256) void k_rows(const float* __restrict__ scores,
                                              float* __restrict__ u,
                                              float* __restrict__ vl, int nb) {
    __shared__ float sch[NN];
    __shared__ float part[4][64];
    const int b = blockIdx.y, t = threadIdx.x;
    const float* srow = scores + (size_t)b * NN;
    for (int q = t * 4; q < NN; q += 1024)
        *reinterpret_cast<float4*>(&sch[q]) =
            *reinterpret_cast<const float4*>(&srow[q]);
    __syncthreads();
    const int r = t & 63;                  // row within block
    const int q = t >> 6;                  // k-quarter (uniform per wave)
    const float si = sch[blockIdx.x * 64 + r];
    float a0=0.f,a1=0.f,a2=0.f,a3=0.f,a4=0.f,a5=0.f,a6=0.f,a7=0.f;
    const int k0 = q * (NN / 4);
    for (int k = k0; k < k0 + NN / 4; k += 8) {
        float4 x = *reinterpret_cast<const float4*>(&sch[k]);
        float4 y = *reinterpret_cast<const float4*>(&sch[k + 4]);
        a0 += fabsf(si - x.x); a1 += fabsf(si - x.y);
        a2 += fabsf(si - x.z); a3 += fabsf(si - x.w);
        a4 += fabsf(si - y.x); a5 += fabsf(si - y.y);
        a6 += fabsf(si - y.z); a7 += fabsf(si - y.w);
    }
    part[q][r] = ((a0 + a1) + (a2 + a3)) + ((a4 + a5) + (a6 + a7));
    __syncthreads();
    if (t < 64) {
        const int ii = blockIdx.x * 64 + t;
        const float B = (part[0][t] + part[1][t]) + (part[2][t] + part[3][t]);
        u[(size_t)b * NN + ii]  = -sch[ii] * LOG2E;
        vl[(size_t)b * NN + ii] = B * LOG2E;
    }
}

// ---------------------------------------------------------------------------
// Kernel B (= R9): per-column softmax constant, 4 cols/thread register
// blocking, interleaved conflict-free LDS reads. Emits w = -m - log2(Z).
__global__ __launch_bounds__(256) void k_cols(const float* __restrict__ u,
                                              const float* __restrict__ vl,
                                              float* __restrict__ w, int nb) {
    __shared__ float su[NN];
    __shared__ float sv[NN];
    __shared__ float pm[32][32];
    __shared__ float pz[32][32];
    __shared__ float fm[32];
    const int b = blockIdx.y, t = threadIdx.x;
    const size_t base = (size_t)b * NN;
    for (int q4 = t * 4; q4 < NN; q4 += 1024) {
        float4 uu = *reinterpret_cast<const float4*>(&u[base + q4]);
        float4 vv = *reinterpret_cast<const float4*>(&vl[base + q4]);
        *reinterpret_cast<float4*>(&su[q4]) = uu;
        sv[q4] = -vv.x; sv[q4+1] = -vv.y; sv[q4+2] = -vv.z; sv[q4+3] = -vv.w;
    }
    __syncthreads();
    const int g = t & 7;                   // column group: 4 cols
    const int q = t >> 3;                  // i-chunk selector (32 chunks)
    const int j0 = blockIdx.x * 32 + g * 4;
    const float c0 = (float)(NN - 1 - 2 * j0);
    const float c1 = c0 - 2.f, c2 = c0 - 4.f, c3 = c0 - 6.f;
    const float4* su4 = reinterpret_cast<const float4*>(su);
    const float4* sv4 = reinterpret_cast<const float4*>(sv);
    float M0 = -3.4e38f, M1 = -3.4e38f, M2 = -3.4e38f, M3 = -3.4e38f;
    for (int k = 0; k < 32; ++k) {
        const int i4 = q + 32 * k;         // interleaved -> conflict-free
        float4 uu = su4[i4], vv = sv4[i4];
        M0 = fmaxf(M0, fmaf(uu.x, c0, vv.x)); M0 = fmaxf(M0, fmaf(uu.y, c0, vv.y));
        M0 = fmaxf(M0, fmaf(uu.z, c0, vv.z)); M0 = fmaxf(M0, fmaf(uu.w, c0, vv.w));
        M1 = fmaxf(M1, fmaf(uu.x, c1, vv.x)); M1 = fmaxf(M1, fmaf(uu.y, c1, vv.y));
        M1 = fmaxf(M1, fmaf(uu.z, c1, vv.z)); M1 = fmaxf(M1, fmaf(uu.w, c1, vv.w));
        M2 = fmaxf(M2, fmaf(uu.x, c2, vv.x)); M2 = fmaxf(M2, fmaf(uu.y, c2, vv.y));
        M2 = fmaxf(M2, fmaf(uu.z, c2, vv.z)); M2 = fmaxf(M2, fmaf(uu.w, c2, vv.w));
        M3 = fmaxf(M3, fmaf(uu.x, c3, vv.x)); M3 = fmaxf(M3, fmaf(uu.y, c3, vv.y));
        M3 = fmaxf(M3, fmaf(uu.z, c3, vv.z)); M3 = fmaxf(M3, fmaf(uu.w, c3, vv.w));
    }
    *reinterpret_cast<float4*>(&pm[q][g * 4]) = make_float4(M0, M1, M2, M3);
    __syncthreads();
    if (t < 32) {
        float m = pm[0][t];
#pragma unroll
        for (int k = 1; k < 32; k++) m = fmaxf(m, pm[k][t]);
        fm[t] = m;
    }
    __syncthreads();
    const float m0 = fm[g * 4], m1 = fm[g * 4 + 1];
    const float m2 = fm[g * 4 + 2], m3 = fm[g * 4 + 3];
    float Z0 = 0.f, Z1 = 0.f, Z2 = 0.f, Z3 = 0.f;
    for (int k = 0; k < 32; ++k) {
        const int i4 = q + 32 * k;
        float4 uu = su4[i4], vv = sv4[i4];
        Z0 += EXP2(fmaf(uu.x, c0, vv.x) - m0); Z0 += EXP2(fmaf(uu.y, c0, vv.y) - m0);
        Z0 += EXP2(fmaf(uu.z, c0, vv.z) - m0); Z0 += EXP2(fmaf(uu.w, c0, vv.w) - m0);
        Z1 += EXP2(fmaf(uu.x, c1, vv.x) - m1); Z1 += EXP2(fmaf(uu.y, c1, vv.y) - m1);
        Z1 += EXP2(fmaf(uu.z, c1, vv.z) - m1); Z1 += EXP2(fmaf(uu.w, c1, vv.w) - m1);
        Z2 += EXP2(fmaf(uu.x, c2, vv.x) - m2); Z2 += EXP2(fmaf(uu.y, c2, vv.y) - m2);
        Z2 += EXP2(fmaf(uu.z, c2, vv.z) - m2); Z2 += EXP2(fmaf(uu.w, c2, vv.w) - m2);
        Z3 += EXP2(fmaf(uu.x, c3, vv.x) - m3); Z3 += EXP2(fmaf(uu.y, c3, vv.y) - m3);
        Z3 += EXP2(fmaf(uu.z, c3, vv.z) - m3); Z3 += EXP2(fmaf(uu.w, c3, vv.w) - m3);
    }
    *reinterpret_cast<float4*>(&pz[q][g * 4]) = make_float4(Z0, Z1, Z2, Z3);
    __syncthreads();
    if (t < 32) {
        float z = 0.f;
#pragma unroll
        for (int k = 0; k < 32; k++) z += pz[k][t];
        w[base + blockIdx.x * 32 + t] = -fm[t] - log2f(z);
    }
}

// ---------------------------------------------------------------------------
// Kernel C: out[b,i,j] = exp2(fma(u_i, c_j, w_j - v_i)) via geometric chain.
// Grid (NN/8, nb), block 256 — block owns 8 full rows = 128 KB contiguous
// (R10 mapping). NEW vs R10: chunk ownership = wv*4 + c (wv = wave id), so
// each wave's 4 successive stores per row are CONSECUTIVE 1 KiB segments
// (4 KB sequential burst per wave), matching the fill kernel's per-wave
// sequential stream. Density/math unchanged.
__global__ __launch_bounds__(256) void k_out(const float* __restrict__ u,
                                             const float* __restrict__ vl,
                                             const float* __restrict__ w,
                                             float* __restrict__ out, int nb) {
    __shared__ float su[8], sv[8], sg[8];
    const int b = blockIdx.y, t = threadIdx.x;
    const int i0 = blockIdx.x * 8;
    if (t < 8) {
        const float uu = u[(size_t)b * NN + i0 + t];
        su[t] = uu;
        sv[t] = vl[(size_t)b * NN + i0 + t];
        sg[t] = EXP2(-2.0f * uu);
    }
    const int wv = t >> 6, lane = t & 63;
    // Per-chunk constants (statically indexed; stays in registers).
    float4 w4[4];
    float d1[4], d2[4], d3[4], cc[4];
    const float* wrow = w + (size_t)b * NN;
#pragma unroll
    for (int c = 0; c < 4; ++c) {
        const int j = (wv * 4 + c) * 256 + lane * 4;
        w4[c] = *reinterpret_cast<const float4*>(wrow + j);
        d1[c] = EXP2(w4[c].y - w4[c].x);
        d2[c] = EXP2(w4[c].z - w4[c].y);
        d3[c] = EXP2(w4[c].w - w4[c].z);
        cc[c] = (float)(NN - 1 - 2 * j);
    }
    __syncthreads();
    float* obase = out + ((size_t)b * NN + i0) * NN;
    for (int r = 0; r < 8; ++r) {
        const float ui = su[r], vi = sv[r], gi = sg[r];
        float* orow = obase + (size_t)r * NN;
#pragma unroll
        for (int c = 0; c < 4; ++c) {
            float4 o;
            o.x = EXP2(fmaf(ui, cc[c], w4[c].x - vi));
            o.y = o.x * (gi * d1[c]);
            o.z = o.y * (gi * d2[c]);
            o.w = o.z * (gi * d3[c]);
            *reinterpret_cast<float4*>(orow + (wv * 4 + c) * 256 + lane * 4) = o;
        }
    }
}

// ---------------------------------------------------------------------------
extern "C" void kernel_launch(void* const* d_in, const int* in_sizes, int n_in,
                              void* d_out, int out_size, void* d_ws, size_t ws_size,
                              hipStream_t stream) {
    const float* scores = (const float*)d_in[0];
    float* out = (float*)d_out;
    const int nb = in_sizes[0] / NN;          // 4 batches
    const size_t S = (size_t)nb * NN;

    float* ws = (float*)d_ws;                 // 3*S floats = 192 KiB
    float* u  = ws;
    float* vl = u + S;
    float* w  = vl + S;

    hipLaunchKernelGGL(k_rows, dim3(NN / 64, nb), dim3(256), 0, stream,
                       scores, u, vl, nb);
    hipLaunchKernelGGL(k_cols, dim3(NN / 32, nb), dim3(256), 0, stream,
                       u, vl, w, nb);
    hipLaunchKernelGGL(k_out, dim3(NN / 8, nb), dim3(256), 0, stream,
                       u, vl, w, out, nb);
}

// Round 13
// 65.277 us; speedup vs baseline: 1.2299x; 1.0029x over previous
//
#include <hip/hip_runtime.h>

#define NN 4096
#define LOG2E 1.44269504088896340736f
#define EXP2(x) __builtin_amdgcn_exp2f(x)

// ---------------------------------------------------------------------------
// Kernel A: per-row stats. Grid (NN/64, nb), block 256. Block stages the full
// 4096-score row (16 KB), 4 threads per row each sum a k-quarter of
// |s_i - s_k|, LDS-merge, emit u = -s*log2e, vl = B*log2e.
__global__ __launch_bounds__(256) void k_rows(const float* __restrict__ scores,
                                              float* __restrict__ u,
                                              float* __restrict__ vl, int nb) {
    __shared__ float sch[NN];
    __shared__ float part[4][64];
    const int b = blockIdx.y, t = threadIdx.x;
    const float* srow = scores + (size_t)b * NN;
    for (int q = t * 4; q < NN; q += 1024)
        *reinterpret_cast<float4*>(&sch[q]) =
            *reinterpret_cast<const float4*>(&srow[q]);
    __syncthreads();
    const int r = t & 63;                  // row within block
    const int q = t >> 6;                  // k-quarter (uniform per wave)
    const float si = sch[blockIdx.x * 64 + r];
    float a0=0.f,a1=0.f,a2=0.f,a3=0.f,a4=0.f,a5=0.f,a6=0.f,a7=0.f;
    const int k0 = q * (NN / 4);
    for (int k = k0; k < k0 + NN / 4; k += 8) {
        float4 x = *reinterpret_cast<const float4*>(&sch[k]);
        float4 y = *reinterpret_cast<const float4*>(&sch[k + 4]);
        a0 += fabsf(si - x.x); a1 += fabsf(si - x.y);
        a2 += fabsf(si - x.z); a3 += fabsf(si - x.w);
        a4 += fabsf(si - y.x); a5 += fabsf(si - y.y);
        a6 += fabsf(si - y.z); a7 += fabsf(si - y.w);
    }
    part[q][r] = ((a0 + a1) + (a2 + a3)) + ((a4 + a5) + (a6 + a7));
    __syncthreads();
    if (t < 64) {
        const int ii = blockIdx.x * 64 + t;
        const float B = (part[0][t] + part[1][t]) + (part[2][t] + part[3][t]);
        u[(size_t)b * NN + ii]  = -sch[ii] * LOG2E;
        vl[(size_t)b * NN + ii] = B * LOG2E;
    }
}

// ---------------------------------------------------------------------------
// Kernel B (= R9): per-column softmax constant, 4 cols/thread register
// blocking, interleaved conflict-free LDS reads. Emits w = -m - log2(Z).
__global__ __launch_bounds__(256) void k_cols(const float* __restrict__ u,
                                              const float* __restrict__ vl,
                                              float* __restrict__ w, int nb) {
    __shared__ float su[NN];
    __shared__ float sv[NN];
    __shared__ float pm[32][32];
    __shared__ float pz[32][32];
    __shared__ float fm[32];
    const int b = blockIdx.y, t = threadIdx.x;
    const size_t base = (size_t)b * NN;
    for (int q4 = t * 4; q4 < NN; q4 += 1024) {
        float4 uu = *reinterpret_cast<const float4*>(&u[base + q4]);
        float4 vv = *reinterpret_cast<const float4*>(&vl[base + q4]);
        *reinterpret_cast<float4*>(&su[q4]) = uu;
        sv[q4] = -vv.x; sv[q4+1] = -vv.y; sv[q4+2] = -vv.z; sv[q4+3] = -vv.w;
    }
    __syncthreads();
    const int g = t & 7;                   // column group: 4 cols
    const int q = t >> 3;                  // i-chunk selector (32 chunks)
    const int j0 = blockIdx.x * 32 + g * 4;
    const float c0 = (float)(NN - 1 - 2 * j0);
    const float c1 = c0 - 2.f, c2 = c0 - 4.f, c3 = c0 - 6.f;
    const float4* su4 = reinterpret_cast<const float4*>(su);
    const float4* sv4 = reinterpret_cast<const float4*>(sv);
    float M0 = -3.4e38f, M1 = -3.4e38f, M2 = -3.4e38f, M3 = -3.4e38f;
    for (int k = 0; k < 32; ++k) {
        const int i4 = q + 32 * k;         // interleaved -> conflict-free
        float4 uu = su4[i4], vv = sv4[i4];
        M0 = fmaxf(M0, fmaf(uu.x, c0, vv.x)); M0 = fmaxf(M0, fmaf(uu.y, c0, vv.y));
        M0 = fmaxf(M0, fmaf(uu.z, c0, vv.z)); M0 = fmaxf(M0, fmaf(uu.w, c0, vv.w));
        M1 = fmaxf(M1, fmaf(uu.x, c1, vv.x)); M1 = fmaxf(M1, fmaf(uu.y, c1, vv.y));
        M1 = fmaxf(M1, fmaf(uu.z, c1, vv.z)); M1 = fmaxf(M1, fmaf(uu.w, c1, vv.w));
        M2 = fmaxf(M2, fmaf(uu.x, c2, vv.x)); M2 = fmaxf(M2, fmaf(uu.y, c2, vv.y));
        M2 = fmaxf(M2, fmaf(uu.z, c2, vv.z)); M2 = fmaxf(M2, fmaf(uu.w, c2, vv.w));
        M3 = fmaxf(M3, fmaf(uu.x, c3, vv.x)); M3 = fmaxf(M3, fmaf(uu.y, c3, vv.y));
        M3 = fmaxf(M3, fmaf(uu.z, c3, vv.z)); M3 = fmaxf(M3, fmaf(uu.w, c3, vv.w));
    }
    *reinterpret_cast<float4*>(&pm[q][g * 4]) = make_float4(M0, M1, M2, M3);
    __syncthreads();
    if (t < 32) {
        float m = pm[0][t];
#pragma unroll
        for (int k = 1; k < 32; k++) m = fmaxf(m, pm[k][t]);
        fm[t] = m;
    }
    __syncthreads();
    const float m0 = fm[g * 4], m1 = fm[g * 4 + 1];
    const float m2 = fm[g * 4 + 2], m3 = fm[g * 4 + 3];
    float Z0 = 0.f, Z1 = 0.f, Z2 = 0.f, Z3 = 0.f;
    for (int k = 0; k < 32; ++k) {
        const int i4 = q + 32 * k;
        float4 uu = su4[i4], vv = sv4[i4];
        Z0 += EXP2(fmaf(uu.x, c0, vv.x) - m0); Z0 += EXP2(fmaf(uu.y, c0, vv.y) - m0);
        Z0 += EXP2(fmaf(uu.z, c0, vv.z) - m0); Z0 += EXP2(fmaf(uu.w, c0, vv.w) - m0);
        Z1 += EXP2(fmaf(uu.x, c1, vv.x) - m1); Z1 += EXP2(fmaf(uu.y, c1, vv.y) - m1);
        Z1 += EXP2(fmaf(uu.z, c1, vv.z) - m1); Z1 += EXP2(fmaf(uu.w, c1, vv.w) - m1);
        Z2 += EXP2(fmaf(uu.x, c2, vv.x) - m2); Z2 += EXP2(fmaf(uu.y, c2, vv.y) - m2);
        Z2 += EXP2(fmaf(uu.z, c2, vv.z) - m2); Z2 += EXP2(fmaf(uu.w, c2, vv.w) - m2);
        Z3 += EXP2(fmaf(uu.x, c3, vv.x) - m3); Z3 += EXP2(fmaf(uu.y, c3, vv.y) - m3);
        Z3 += EXP2(fmaf(uu.z, c3, vv.z) - m3); Z3 += EXP2(fmaf(uu.w, c3, vv.w) - m3);
    }
    *reinterpret_cast<float4*>(&pz[q][g * 4]) = make_float4(Z0, Z1, Z2, Z3);
    __syncthreads();
    if (t < 32) {
        float z = 0.f;
#pragma unroll
        for (int k = 0; k < 32; k++) z += pz[k][t];
        w[base + blockIdx.x * 32 + t] = -fm[t] - log2f(z);
    }
}

// ---------------------------------------------------------------------------
// Kernel C: out[b,i,j] = exp2(fma(u_i, c_j, w_j - v_i)).
// Grid (NN/8, nb), block 256; block owns 8 full rows = 128 KB contiguous;
// wave-sequential chunk ownership (R12). NEW: __launch_bounds__(256, 8)
// forces <=64 VGPR -> guaranteed 8 blocks/CU (32 waves/CU) for maximal
// outstanding-store depth; direct 4-exp form (exp count proven free in
// R7/R11) keeps persistent state to ~28 floats so the cap doesn't spill.
__global__ __launch_bounds__(256, 8) void k_out(const float* __restrict__ u,
                                                const float* __restrict__ vl,
                                                const float* __restrict__ w,
                                                float* __restrict__ out, int nb) {
    __shared__ float su[8], sv[8];
    const int b = blockIdx.y, t = threadIdx.x;
    const int i0 = blockIdx.x * 8;
    if (t < 8) {
        su[t] = u[(size_t)b * NN + i0 + t];
        sv[t] = vl[(size_t)b * NN + i0 + t];
    }
    const int wv = t >> 6, lane = t & 63;
    float4 w4[4];
    float cc[4];
    const float* wrow = w + (size_t)b * NN;
#pragma unroll
    for (int c = 0; c < 4; ++c) {
        const int j = (wv * 4 + c) * 256 + lane * 4;
        w4[c] = *reinterpret_cast<const float4*>(wrow + j);
        cc[c] = (float)(NN - 1 - 2 * j);
    }
    __syncthreads();
    float* obase = out + ((size_t)b * NN + i0) * NN;
    for (int r = 0; r < 8; ++r) {
        const float ui = su[r], vi = sv[r];
        float* orow = obase + (size_t)r * NN;
#pragma unroll
        for (int c = 0; c < 4; ++c) {
            const float c0 = cc[c];
            float4 o;
            o.x = EXP2(fmaf(ui, c0,       w4[c].x - vi));
            o.y = EXP2(fmaf(ui, c0 - 2.f, w4[c].y - vi));
            o.z = EXP2(fmaf(ui, c0 - 4.f, w4[c].z - vi));
            o.w = EXP2(fmaf(ui, c0 - 6.f, w4[c].w - vi));
            *reinterpret_cast<float4*>(orow + (wv * 4 + c) * 256 + lane * 4) = o;
        }
    }
}

// ---------------------------------------------------------------------------
extern "C" void kernel_launch(void* const* d_in, const int* in_sizes, int n_in,
                              void* d_out, int out_size, void* d_ws, size_t ws_size,
                              hipStream_t stream) {
    const float* scores = (const float*)d_in[0];
    float* out = (float*)d_out;
    const int nb = in_sizes[0] / NN;          // 4 batches
    const size_t S = (size_t)nb * NN;

    float* ws = (float*)d_ws;                 // 3*S floats = 192 KiB
    float* u  = ws;
    float* vl = u + S;
    float* w  = vl + S;

    hipLaunchKernelGGL(k_rows, dim3(NN / 64, nb), dim3(256), 0, stream,
                       scores, u, vl, nb);
    hipLaunchKernelGGL(k_cols, dim3(NN / 32, nb), dim3(256), 0, stream,
                       u, vl, w, nb);
    hipLaunchKernelGGL(k_out, dim3(NN / 8, nb), dim3(256), 0, stream,
                       u, vl, w, out, nb);
}